// Round 9
// baseline (156.247 us; speedup 1.0000x reference)
//
#include <hip/hip_runtime.h>
#include <stdint.h>

#define Bb 8
#define PREK 1024
#define POSTK 300
#define NBIN 120            // scores 9..127 -> bin = s-9
#define NCHUNK 512          // 256-candidate chunks per batch

__device__ __forceinline__ float clampb(float v){ return fminf(fmaxf(v, 0.0f), 1024.0f); }

// K1: best score + first-argmax per anchor (int4 vectorized), packed u16 [(s+128)<<8|lab]
//     layout sc16[b][a][h*128+w]; per-32w-chunk histogram -> chist[(b*512+ci)*120+bin]
__global__ void __launch_bounds__(256) k1_scores(const int* __restrict__ data,
                                                 unsigned short* __restrict__ sc16,
                                                 int* __restrict__ chist){
    int blk = blockIdx.x;                 // 8*128: (b, h)
    int b = blk >> 7, h = blk & 127;
    int tid = threadIdx.x;
    int a = tid >> 5, wg = tid & 31;
    int w = wg << 2;
    const int* p = data + (((size_t)(b*96 + a*12 + 4)) << 14) + (h << 7) + w;
    int4 m = *(const int4*)p;
    int4 lb = make_int4(0,0,0,0);
#pragma unroll
    for (int c = 1; c < 8; ++c){
        int4 v = *(const int4*)(p + ((size_t)c << 14));
        if (v.x > m.x){ m.x = v.x; lb.x = c; }
        if (v.y > m.y){ m.y = v.y; lb.y = c; }
        if (v.z > m.z){ m.z = v.z; lb.z = c; }
        if (v.w > m.w){ m.w = v.w; lb.w = c; }
    }
    ushort4 st;
    st.x = (unsigned short)(((m.x + 128) << 8) | lb.x);
    st.y = (unsigned short)(((m.y + 128) << 8) | lb.y);
    st.z = (unsigned short)(((m.z + 128) << 8) | lb.z);
    st.w = (unsigned short)(((m.w + 128) << 8) | lb.w);
    *(ushort4*)(sc16 + (((size_t)(b*8 + a)) << 14) + (h << 7) + w) = st;

    __shared__ int hist[4][NBIN];
    for (int i = tid; i < 4*NBIN; i += 256) ((int*)hist)[i] = 0;
    __syncthreads();
    int q = wg >> 3;
    if (m.x >= 9) atomicAdd(&hist[q][m.x-9], 1);
    if (m.y >= 9) atomicAdd(&hist[q][m.y-9], 1);
    if (m.z >= 9) atomicAdd(&hist[q][m.z-9], 1);
    if (m.w >= 9) atomicAdd(&hist[q][m.w-9], 1);
    __syncthreads();
    int* cb = chist + ((size_t)(b*NCHUNK + h*4)) * NBIN;
    for (int i = tid; i < 4*NBIN; i += 256) cb[i] = ((int*)hist)[i];
}

// K2: per batch: column-sum global hist (coalesced, no atomics), suffix -> gt/T,
//     init dmeta, then exclusive chunk-scan for bins >= T
__global__ void __launch_bounds__(256) k2_select(int* __restrict__ chist, int* __restrict__ gt,
                                                 int* __restrict__ Tb_, int* __restrict__ dmeta){
    int b = blockIdx.x, tid = threadIdx.x;
    __shared__ int hs2[2][NBIN];
    __shared__ int suf[128];
    __shared__ int Tsh;
    __shared__ int sb[512];
    if (tid == 0) Tsh = -1;
    int half = tid >> 7, bin = tid & 127;
    const int* cb = chist + (size_t)b * NCHUNK * NBIN;
    if (bin < NBIN){
        int s = 0;
        const int* p2 = cb + (size_t)half*256*NBIN + bin;
#pragma unroll 8
        for (int ch = 0; ch < 256; ++ch) s += p2[(size_t)ch * NBIN];
        hs2[half][bin] = s;
    }
    __syncthreads();
    int hbin = 0;
    if (tid < 128){
        hbin = (tid < NBIN) ? hs2[0][tid] + hs2[1][tid] : 0;
        suf[tid] = hbin;
    }
    __syncthreads();
    for (int off = 1; off < 128; off <<= 1){
        int v = 0;
        if (tid < 128 && tid + off < 128) v = suf[tid + off];
        __syncthreads();
        if (tid < 128) suf[tid] += v;
        __syncthreads();
    }
    if (tid < NBIN){
        gt[b*128 + tid] = suf[tid] - hbin;
        if (suf[tid] >= PREK) atomicMax(&Tsh, tid);
    }
    __syncthreads();
    int T = Tsh > 0 ? Tsh : 0;
    if (tid == 0) Tb_[b] = T;
    for (int k = tid; k < PREK; k += 256) dmeta[b*PREK + k] = -1;
    int i0 = tid, i1 = tid + 256;
    for (int abin = T; abin < NBIN; ++abin){
        int* basep = chist + (size_t)(b*NCHUNK) * NBIN + abin;
        int v0 = basep[(size_t)i0 * NBIN], v1 = basep[(size_t)i1 * NBIN];
        sb[i0] = v0; sb[i1] = v1;
        __syncthreads();
        for (int off = 1; off < 512; off <<= 1){
            int a0 = (i0 >= off) ? sb[i0 - off] : 0;
            int a1 = (i1 >= off) ? sb[i1 - off] : 0;
            __syncthreads();
            sb[i0] += a0; sb[i1] += a1;
            __syncthreads();
        }
        basep[(size_t)i0 * NBIN] = sb[i0] - v0;
        basep[(size_t)i1 * NBIN] = sb[i1] - v1;
        __syncthreads();
    }
}

// K3: stable rank via ballots + cross-wave hist; ranked candidates decode their box
//     bit-exact and scatter dbox/dmeta by rank
__global__ void __launch_bounds__(256) k3_rank(const unsigned short* __restrict__ sc16,
                                               const int* __restrict__ chist,
                                               const int* __restrict__ gt, const int* __restrict__ Tb_,
                                               const int* __restrict__ data,
                                               const float* __restrict__ anchors,
                                               const int* __restrict__ etab,
                                               float4* __restrict__ dbox, int* __restrict__ dmeta){
    int blk = blockIdx.x;                // 8*512: (b, ci)
    int b = blk >> 9, ci = blk & 511;
    int tid = threadIdx.x;
    int h = ci >> 2, w0 = (ci & 3) << 5;
    __shared__ unsigned short sc[256];
    __shared__ int wcnt[4][NBIN];
    if (tid < 64){
        int a = tid & 7, wq = tid >> 3;
        ushort4 v4 = *(const ushort4*)(sc16 + (((size_t)(b*8 + a)) << 14) + (h << 7) + w0 + (wq << 2));
        sc[(wq*4 + 0)*8 + a] = v4.x;
        sc[(wq*4 + 1)*8 + a] = v4.y;
        sc[(wq*4 + 2)*8 + a] = v4.z;
        sc[(wq*4 + 3)*8 + a] = v4.w;
    }
    for (int i = tid; i < 4*NBIN; i += 256) ((int*)wcnt)[i] = 0;
    int T = Tb_[b];
    __syncthreads();
    unsigned short v = sc[tid];
    int s = (int)(v >> 8) - 128;
    int bin = s - 9;
    bool qual = (bin >= T);
    int wv = tid >> 6, lane = tid & 63;
    if (qual) atomicAdd(&wcnt[wv][bin], 1);
    __syncthreads();
    int myeq = 0;
    {
        unsigned long long low = (1ull << lane) - 1ull;
        for (int vb = T; vb < NBIN; ++vb){
            unsigned long long bal = __ballot(qual && bin == vb);
            if (!bal) continue;
            if (qual && bin == vb) myeq = __popcll(bal & low);
        }
    }
    if (!qual) return;
    int cross = 0;
    for (int w2 = 0; w2 < wv; ++w2) cross += wcnt[w2][bin];
    int rank = gt[b*128 + bin] + chist[((size_t)(b*NCHUNK) + ci)*NBIN + bin] + cross + myeq;
    if (rank < PREK){
        int n = ci*256 + tid;               // == ((h*128+w)*8 + a)
        int a = n & 7, wc = (n >> 3) & 127;
        const int* p = data + (((size_t)(b*96 + a*12)) << 14) + (h << 7) + wc;
        int d0 = p[0], d1 = p[1 << 14], d2 = p[2 << 14], d3 = p[3 << 14];
        float4 an = ((const float4*)anchors)[n];
        float cx = __fmul_rn(__fadd_rn(an.x, an.z), 0.5f);
        float cy = __fmul_rn(__fadd_rn(an.y, an.w), 0.5f);
        float wx = __fsub_rn(an.z, an.x), wy = __fsub_rn(an.w, an.y);
        float dx = __fmul_rn((float)d0, 0.0625f), dy = __fmul_rn((float)d1, 0.0625f);
        float ex = __fmul_rn((float)etab[d2 + 128], 0.0625f);
        float ey = __fmul_rn((float)etab[d3 + 128], 0.0625f);
        float pcx = __fadd_rn(cx, __fmul_rn(dx, wx));
        float pcy = __fadd_rn(cy, __fmul_rn(dy, wy));
        float hx = __fmul_rn(__fmul_rn(wx, ex), 0.5f);
        float hy = __fmul_rn(__fmul_rn(wy, ey), 0.5f);
        float x1 = clampb(__fsub_rn(pcx, hx)), y1 = clampb(__fsub_rn(pcy, hy));
        float x2 = clampb(__fadd_rn(pcx, hx)), y2 = clampb(__fadd_rn(pcy, hy));
        dbox[b*PREK + rank] = make_float4(x1, y1, x2, y2);
        dmeta[b*PREK + rank] = (int)v;
    }
}

// K45: per batch, 512 thr (8 waves, one class each): stable 2-pass partition,
//      register-resident shfl-based NMS (unrolled, no spills), 2-pass compaction
__global__ void __launch_bounds__(512, 2) k45_nms_out(const float4* __restrict__ dbox,
                                                      const int* __restrict__ dmeta,
                                                      float* __restrict__ out){
    int b = blockIdx.x, tid = threadIdx.x, lane = tid & 63, wv = tid >> 6;
    __shared__ float X1[1024], Y1[1024], X2[1024], Y2[1024], AR[1024];
    __shared__ unsigned char KEEP[1024];
    __shared__ int wq[8][8], wq2[8][8];
    __shared__ int cbs[8], ccn[8];
    __shared__ int wcn[8];
    __shared__ int pbase;

    // phase 1: two entries per thread, stable per-class partition
    int v0 = dmeta[b*PREK + tid];
    int v1 = dmeta[b*PREK + 512 + tid];
    float4 bb0 = dbox[b*PREK + tid];
    float4 bb1 = dbox[b*PREK + 512 + tid];
    bool valid0 = (v0 >= 0), valid1 = (v1 >= 0);
    int lc0 = valid0 ? (v0 & 255) : -1;
    int lc1 = valid1 ? (v1 & 255) : -1;
    KEEP[tid] = 0; KEEP[tid + 512] = 0;
    if (tid == 0) pbase = 0;
    int win0 = 0, win1 = 0;
#pragma unroll
    for (int c = 0; c < 8; ++c){
        unsigned long long bal0 = __ballot(lc0 == c);
        unsigned long long bal1 = __ballot(lc1 == c);
        if (lane == 0){ wq[wv][c] = __popcll(bal0); wq2[wv][c] = __popcll(bal1); }
        if (lc0 == c) win0 = __popcll(bal0 & ((1ull << lane) - 1ull));
        if (lc1 == c) win1 = __popcll(bal1 & ((1ull << lane) - 1ull));
    }
    __syncthreads();
    if (tid < 8){
        int run = 0;
        for (int w2 = 0; w2 < 8; ++w2){ int t = wq[w2][tid];  wq[w2][tid]  = run; run += t; }
        for (int w2 = 0; w2 < 8; ++w2){ int t = wq2[w2][tid]; wq2[w2][tid] = run; run += t; }
        ccn[tid] = run;
    }
    __syncthreads();
    if (tid == 0){
        int run = 0;
        for (int c = 0; c < 8; ++c){ cbs[c] = run; run += ccn[c]; }
    }
    __syncthreads();
    int p0 = 0, p1 = 0;
    if (valid0){
        p0 = cbs[lc0] + wq[wv][lc0] + win0;
        float off = (float)(lc0 << 12);
        float ox1 = __fadd_rn(bb0.x, off), oy1 = __fadd_rn(bb0.y, off);
        float ox2 = __fadd_rn(bb0.z, off), oy2 = __fadd_rn(bb0.w, off);
        X1[p0] = ox1; Y1[p0] = oy1; X2[p0] = ox2; Y2[p0] = oy2;
        AR[p0] = __fmul_rn(__fsub_rn(ox2, ox1), __fsub_rn(oy2, oy1));
    }
    if (valid1){
        p1 = cbs[lc1] + wq2[wv][lc1] + win1;
        float off = (float)(lc1 << 12);
        float ox1 = __fadd_rn(bb1.x, off), oy1 = __fadd_rn(bb1.y, off);
        float ox2 = __fadd_rn(bb1.z, off), oy2 = __fadd_rn(bb1.w, off);
        X1[p1] = ox1; Y1[p1] = oy1; X2[p1] = ox2; Y2[p1] = oy2;
        AR[p1] = __fmul_rn(__fsub_rn(ox2, ox1), __fsub_rn(oy2, oy1));
    }
    __syncthreads();

    // phase 2: NMS, one wave per class
    {
        int M = ccn[wv], base = cbs[wv];
        if (M > 0 && M <= 256){
            // lane owns rows lane+64g; columns == rows, fetched via shfl
            float rx1[4], ry1[4], rx2[4], ry2[4], rar[4];
#pragma unroll
            for (int g = 0; g < 4; ++g){
                int r = g*64 + lane;
                int ad = base + ((r < M) ? r : 0);
                rx1[g]=X1[ad]; ry1[g]=Y1[ad]; rx2[g]=X2[ad]; ry2[g]=Y2[ad]; rar[g]=AR[ad];
            }
            unsigned long long mk[4][4];   // [row-group][col-word], static-indexed
#pragma unroll
            for (int g = 0; g < 4; ++g)
#pragma unroll
                for (int w2 = 0; w2 < 4; ++w2) mk[g][w2] = 0ull;

            // build: fixed-bound unrolled column loop; column box via register shfl
#pragma unroll
            for (int jw = 0; jw < 4; ++jw){
                if (jw*64 < M){
                    int limj = M - jw*64; if (limj > 64) limj = 64;
#pragma unroll 8
                    for (int jl = 0; jl < 64; ++jl){
                        if (jl < limj){
                            int j = jw*64 + jl;
                            float jx1 = __shfl(rx1[jw], jl);
                            float jy1 = __shfl(ry1[jw], jl);
                            float jx2 = __shfl(rx2[jw], jl);
                            float jy2 = __shfl(ry2[jw], jl);
                            float jar = __shfl(rar[jw], jl);
#pragma unroll
                            for (int g = 0; g < 4; ++g){
                                if (g*64 < M){
                                    int i = g*64 + lane;
                                    float wx = fmaxf(__fsub_rn(fminf(rx2[g], jx2), fmaxf(rx1[g], jx1)), 0.0f);
                                    float wy = fmaxf(__fsub_rn(fminf(ry2[g], jy2), fmaxf(ry1[g], jy1)), 0.0f);
                                    float inter = __fmul_rn(wx, wy);
                                    float den = __fadd_rn(__fsub_rn(__fadd_rn(rar[g], jar), inter), 1e-9f);
                                    bool o = (__fdiv_rn(inter, den) > 0.5f) && (j > i);
                                    mk[g][jw] |= o ? (1ull << jl) : 0ull;
                                }
                            }
                        }
                    }
                }
            }

            // walk: branchless — unconditional shfls (pipelined), masked ORs
            unsigned long long r0=0ull, r1=0ull, r2=0ull, r3=0ull;
#pragma unroll
            for (int iw = 0; iw < 4; ++iw){
                if (iw*64 < M){
                    int limi = M - iw*64; if (limi > 64) limi = 64;
#pragma unroll 8
                    for (int il = 0; il < 64; ++il){
                        if (il < limi){
                            unsigned long long cur = (iw==0)?r0:(iw==1)?r1:(iw==2)?r2:r3;
                            unsigned long long w0 = __shfl(mk[iw][0], il);
                            unsigned long long w1 = __shfl(mk[iw][1], il);
                            unsigned long long w2_ = __shfl(mk[iw][2], il);
                            unsigned long long w3_ = __shfl(mk[iw][3], il);
                            unsigned long long msk = ((cur >> il) & 1ull) ? 0ull : ~0ull;
                            r0 |= w0 & msk; r1 |= w1 & msk; r2 |= w2_ & msk; r3 |= w3_ & msk;
                        }
                    }
                }
            }
#pragma unroll
            for (int g = 0; g < 4; ++g){
                int r = g*64 + lane;
                unsigned long long rg = (g==0)?r0:(g==1)?r1:(g==2)?r2:r3;
                if (r < M) KEEP[base + r] = (unsigned char)(((rg >> lane) & 1ull) ^ 1ull);
            }
        } else if (M > 256){
            // fallback: wave-serial greedy in LDS
            for (int m = lane; m < M; m += 64) KEEP[base+m] = 0;   // 1 = suppressed
            for (int i = 0; i < M; ++i){
                if (KEEP[base+i]) continue;
                float xi1 = X1[base+i], yi1 = Y1[base+i];
                float xi2 = X2[base+i], yi2 = Y2[base+i], ai = AR[base+i];
                for (int j = i + 1 + lane; j < M; j += 64){
                    if (KEEP[base+j]) continue;
                    float wx = fmaxf(__fsub_rn(fminf(xi2, X2[base+j]), fmaxf(xi1, X1[base+j])), 0.0f);
                    float wy = fmaxf(__fsub_rn(fminf(yi2, Y2[base+j]), fmaxf(yi1, Y1[base+j])), 0.0f);
                    float inter = __fmul_rn(wx, wy);
                    float den = __fadd_rn(__fsub_rn(__fadd_rn(ai, AR[base+j]), inter), 1e-9f);
                    if (__fdiv_rn(inter, den) > 0.5f) KEEP[base+j] = 1;
                }
            }
            for (int m = lane; m < M; m += 64) KEEP[base+m] ^= 1;  // -> 1 = keep
        }
    }
    __syncthreads();

    // phase 3: rank-ordered compaction to first 300 (two passes)
    float* boxes  = out;
    float* scores = out + Bb*POSTK*4;
    float* labs   = out + Bb*POSTK*5;
#pragma unroll
    for (int pass = 0; pass < 2; ++pass){
        bool vld   = pass ? valid1 : valid0;
        int  pp    = pass ? p1 : p0;
        int  lcc   = pass ? lc1 : lc0;
        int  vv    = pass ? v1 : v0;
        float4 bbb = pass ? bb1 : bb0;
        bool kp = vld && (KEEP[pp] != 0);
        unsigned long long bal = __ballot(kp);
        if (lane == 0) wcn[wv] = __popcll(bal);
        __syncthreads();
        if (tid == 0){
            int r = pbase;
            for (int w2 = 0; w2 < 8; ++w2){ int t = wcn[w2]; wcn[w2] = r; r += t; }
            pbase = r;
        }
        __syncthreads();
        int pos = wcn[wv] + __popcll(bal & ((1ull << lane) - 1ull));
        if (kp && pos < POSTK){
            float sval = __fmul_rn((float)((vv >> 8) - 128), 0.0625f);
            int o = (b*POSTK + pos)*4;
            boxes[o+0] = bbb.x; boxes[o+1] = bbb.y; boxes[o+2] = bbb.z; boxes[o+3] = bbb.w;
            scores[b*POSTK + pos] = sval;
            labs[b*POSTK + pos] = (float)lcc;
        }
        __syncthreads();
    }
    int tot = pbase < POSTK ? pbase : POSTK;
    if (tid >= tot && tid < POSTK){
        int o = (b*POSTK + tid)*4;
        boxes[o+0] = 0.f; boxes[o+1] = 0.f; boxes[o+2] = 0.f; boxes[o+3] = 0.f;
        scores[b*POSTK + tid] = 0.f;
        labs[b*POSTK + tid] = -1.0f;
    }
}

extern "C" void kernel_launch(void* const* d_in, const int* in_sizes, int n_in,
                              void* d_out, int out_size, void* d_ws, size_t ws_size,
                              hipStream_t stream) {
    const int*   data    = (const int*)d_in[0];
    const float* anchors = (const float*)d_in[1];
    const int*   etab    = (const int*)d_in[2];
    float* out = (float*)d_out;

    char* ws = (char*)d_ws;
    size_t off = 0;
    auto alloc = [&](size_t bytes)->char*{ char* p = ws + off; off += (bytes + 255) & ~(size_t)255; return p; };
    unsigned short* sc16 = (unsigned short*)alloc((size_t)Bb*8*16384*2);   // 2 MB
    int* chist           = (int*)alloc((size_t)Bb*NCHUNK*NBIN*4);          // 1.9 MB
    int* gt              = (int*)alloc((size_t)Bb*128*4);
    int* Tb_             = (int*)alloc((size_t)Bb*4);
    float4* dbox         = (float4*)alloc((size_t)Bb*PREK*16);             // 128 KB
    int* dmeta           = (int*)alloc((size_t)Bb*PREK*4);                 // 32 KB
    (void)ws_size; (void)in_sizes; (void)n_in; (void)out_size;

    k1_scores<<<Bb*128, 256, 0, stream>>>(data, sc16, chist);
    k2_select<<<Bb, 256, 0, stream>>>(chist, gt, Tb_, dmeta);
    k3_rank<<<Bb*NCHUNK, 256, 0, stream>>>(sc16, chist, gt, Tb_, data, anchors, etab, dbox, dmeta);
    k45_nms_out<<<Bb, 512, 0, stream>>>(dbox, dmeta, out);
}

// Round 10
// 143.934 us; speedup vs baseline: 1.0855x; 1.0855x over previous
//
#include <hip/hip_runtime.h>
#include <stdint.h>

#define Bb 8
#define PREK 1024
#define POSTK 300
#define NBIN 120            // scores 9..127 -> bin = s-9
#define NCHUNK 512          // 256-candidate chunks per batch

__device__ __forceinline__ float clampb(float v){ return fminf(fmaxf(v, 0.0f), 1024.0f); }

// K1: best score + first-argmax per anchor (int4 vectorized), packed u16 [(s+128)<<8|lab]
//     layout sc16[b][a][h*128+w]; per-32w-chunk histogram -> chist[(b*512+ci)*120+bin]
__global__ void __launch_bounds__(256) k1_scores(const int* __restrict__ data,
                                                 unsigned short* __restrict__ sc16,
                                                 int* __restrict__ chist){
    int blk = blockIdx.x;                 // 8*128: (b, h)
    int b = blk >> 7, h = blk & 127;
    int tid = threadIdx.x;
    int a = tid >> 5, wg = tid & 31;
    int w = wg << 2;
    const int* p = data + (((size_t)(b*96 + a*12 + 4)) << 14) + (h << 7) + w;
    int4 m = *(const int4*)p;
    int4 lb = make_int4(0,0,0,0);
#pragma unroll
    for (int c = 1; c < 8; ++c){
        int4 v = *(const int4*)(p + ((size_t)c << 14));
        if (v.x > m.x){ m.x = v.x; lb.x = c; }
        if (v.y > m.y){ m.y = v.y; lb.y = c; }
        if (v.z > m.z){ m.z = v.z; lb.z = c; }
        if (v.w > m.w){ m.w = v.w; lb.w = c; }
    }
    ushort4 st;
    st.x = (unsigned short)(((m.x + 128) << 8) | lb.x);
    st.y = (unsigned short)(((m.y + 128) << 8) | lb.y);
    st.z = (unsigned short)(((m.z + 128) << 8) | lb.z);
    st.w = (unsigned short)(((m.w + 128) << 8) | lb.w);
    *(ushort4*)(sc16 + (((size_t)(b*8 + a)) << 14) + (h << 7) + w) = st;

    __shared__ int hist[4][NBIN];
    for (int i = tid; i < 4*NBIN; i += 256) ((int*)hist)[i] = 0;
    __syncthreads();
    int q = wg >> 3;
    if (m.x >= 9) atomicAdd(&hist[q][m.x-9], 1);
    if (m.y >= 9) atomicAdd(&hist[q][m.y-9], 1);
    if (m.z >= 9) atomicAdd(&hist[q][m.z-9], 1);
    if (m.w >= 9) atomicAdd(&hist[q][m.w-9], 1);
    __syncthreads();
    int* cb = chist + ((size_t)(b*NCHUNK + h*4)) * NBIN;
    for (int i = tid; i < 4*NBIN; i += 256) cb[i] = ((int*)hist)[i];
}

// K2: per batch (1024 thr): coalesced 8-group histogram reduce, suffix -> gt/T,
//     init dmeta, 512-thread exclusive chunk-scan for bins >= T
__global__ void __launch_bounds__(1024) k2_select(int* __restrict__ chist, int* __restrict__ gt,
                                                  int* __restrict__ Tb_, int* __restrict__ dmeta){
    int b = blockIdx.x, tid = threadIdx.x;
    __shared__ int part[8][NBIN];
    __shared__ int hs[NBIN];
    __shared__ int suf[128];
    __shared__ int Tsh;
    __shared__ int sb[512];
    if (tid == 0) Tsh = -1;
    const int* cb = chist + (size_t)b * NCHUNK * NBIN;
    if (tid < 8*NBIN){
        int g = tid / NBIN, bin = tid - g*NBIN;
        int s = 0;
        const int* p2 = cb + (size_t)g*64*NBIN + bin;
#pragma unroll 8
        for (int ch = 0; ch < 64; ++ch) s += p2[(size_t)ch * NBIN];
        part[g][bin] = s;
    }
    __syncthreads();
    if (tid < NBIN){
        int s = 0;
#pragma unroll
        for (int g = 0; g < 8; ++g) s += part[g][tid];
        hs[tid] = s;
    }
    __syncthreads();
    int hbin = 0;
    if (tid < 128){
        hbin = (tid < NBIN) ? hs[tid] : 0;
        suf[tid] = hbin;
    }
    __syncthreads();
    for (int off = 1; off < 128; off <<= 1){
        int v = 0;
        if (tid < 128 && tid + off < 128) v = suf[tid + off];
        __syncthreads();
        if (tid < 128) suf[tid] += v;
        __syncthreads();
    }
    if (tid < NBIN){
        gt[b*128 + tid] = suf[tid] - hbin;
        if (suf[tid] >= PREK) atomicMax(&Tsh, tid);
    }
    __syncthreads();
    int T = Tsh > 0 ? Tsh : 0;
    if (tid == 0) Tb_[b] = T;
    dmeta[b*PREK + tid] = -1;
    for (int abin = T; abin < NBIN; ++abin){
        int* basep = chist + (size_t)(b*NCHUNK) * NBIN + abin;
        int v = 0;
        if (tid < 512){ v = basep[(size_t)tid * NBIN]; sb[tid] = v; }
        __syncthreads();
        for (int off = 1; off < 512; off <<= 1){
            int a2 = 0;
            if (tid < 512 && tid >= off) a2 = sb[tid - off];
            __syncthreads();
            if (tid < 512) sb[tid] += a2;
            __syncthreads();
        }
        if (tid < 512) basep[(size_t)tid * NBIN] = sb[tid] - v;
        __syncthreads();
    }
}

// K3: stable rank via ballots + cross-wave hist; ranked candidates decode their box
//     bit-exact and scatter dbox/dmeta by rank
__global__ void __launch_bounds__(256) k3_rank(const unsigned short* __restrict__ sc16,
                                               const int* __restrict__ chist,
                                               const int* __restrict__ gt, const int* __restrict__ Tb_,
                                               const int* __restrict__ data,
                                               const float* __restrict__ anchors,
                                               const int* __restrict__ etab,
                                               float4* __restrict__ dbox, int* __restrict__ dmeta){
    int blk = blockIdx.x;                // 8*512: (b, ci)
    int b = blk >> 9, ci = blk & 511;
    int tid = threadIdx.x;
    int h = ci >> 2, w0 = (ci & 3) << 5;
    __shared__ unsigned short sc[256];
    __shared__ int wcnt[4][NBIN];
    if (tid < 64){
        int a = tid & 7, wq = tid >> 3;
        ushort4 v4 = *(const ushort4*)(sc16 + (((size_t)(b*8 + a)) << 14) + (h << 7) + w0 + (wq << 2));
        sc[(wq*4 + 0)*8 + a] = v4.x;
        sc[(wq*4 + 1)*8 + a] = v4.y;
        sc[(wq*4 + 2)*8 + a] = v4.z;
        sc[(wq*4 + 3)*8 + a] = v4.w;
    }
    for (int i = tid; i < 4*NBIN; i += 256) ((int*)wcnt)[i] = 0;
    int T = Tb_[b];
    __syncthreads();
    unsigned short v = sc[tid];
    int s = (int)(v >> 8) - 128;
    int bin = s - 9;
    bool qual = (bin >= T);
    int wv = tid >> 6, lane = tid & 63;
    if (qual) atomicAdd(&wcnt[wv][bin], 1);
    __syncthreads();
    int myeq = 0;
    {
        unsigned long long low = (1ull << lane) - 1ull;
        for (int vb = T; vb < NBIN; ++vb){
            unsigned long long bal = __ballot(qual && bin == vb);
            if (!bal) continue;
            if (qual && bin == vb) myeq = __popcll(bal & low);
        }
    }
    if (!qual) return;
    int cross = 0;
    for (int w2 = 0; w2 < wv; ++w2) cross += wcnt[w2][bin];
    int rank = gt[b*128 + bin] + chist[((size_t)(b*NCHUNK) + ci)*NBIN + bin] + cross + myeq;
    if (rank < PREK){
        int n = ci*256 + tid;               // == ((h*128+w)*8 + a)
        int a = n & 7, wc = (n >> 3) & 127;
        const int* p = data + (((size_t)(b*96 + a*12)) << 14) + (h << 7) + wc;
        int d0 = p[0], d1 = p[1 << 14], d2 = p[2 << 14], d3 = p[3 << 14];
        float4 an = ((const float4*)anchors)[n];
        float cx = __fmul_rn(__fadd_rn(an.x, an.z), 0.5f);
        float cy = __fmul_rn(__fadd_rn(an.y, an.w), 0.5f);
        float wx = __fsub_rn(an.z, an.x), wy = __fsub_rn(an.w, an.y);
        float dx = __fmul_rn((float)d0, 0.0625f), dy = __fmul_rn((float)d1, 0.0625f);
        float ex = __fmul_rn((float)etab[d2 + 128], 0.0625f);
        float ey = __fmul_rn((float)etab[d3 + 128], 0.0625f);
        float pcx = __fadd_rn(cx, __fmul_rn(dx, wx));
        float pcy = __fadd_rn(cy, __fmul_rn(dy, wy));
        float hx = __fmul_rn(__fmul_rn(wx, ex), 0.5f);
        float hy = __fmul_rn(__fmul_rn(wy, ey), 0.5f);
        float x1 = clampb(__fsub_rn(pcx, hx)), y1 = clampb(__fsub_rn(pcy, hy));
        float x2 = clampb(__fadd_rn(pcx, hx)), y2 = clampb(__fadd_rn(pcy, hy));
        dbox[b*PREK + rank] = make_float4(x1, y1, x2, y2);
        dmeta[b*PREK + rank] = (int)v;
    }
}

// NG-templated register NMS: rows lane+64g; mask words only for upper triangle
// (g<=jw), walk shfls only words w>=iw. Greedy order identical to reference.
template<int NG>
__device__ __forceinline__ void nms_reg(const float* __restrict__ X1, const float* __restrict__ Y1,
                                        const float* __restrict__ X2, const float* __restrict__ Y2,
                                        const float* __restrict__ AR,
                                        int base, int M, int lane, unsigned char* __restrict__ KEEP){
    float rx1[NG], ry1[NG], rx2[NG], ry2[NG], rar[NG];
#pragma unroll
    for (int g = 0; g < NG; ++g){
        int r = g*64 + lane;
        int ad = base + ((r < M) ? r : 0);
        rx1[g]=X1[ad]; ry1[g]=Y1[ad]; rx2[g]=X2[ad]; ry2[g]=Y2[ad]; rar[g]=AR[ad];
    }
    unsigned long long mk[NG][NG];
#pragma unroll
    for (int g = 0; g < NG; ++g)
#pragma unroll
        for (int c = 0; c < NG; ++c) mk[g][c] = 0ull;

    // build: column j broadcast via shfl of register rows; area derived (bit-exact)
#pragma unroll
    for (int jw = 0; jw < NG; ++jw){
        if (jw*64 < M){
            int limj = M - jw*64; if (limj > 64) limj = 64;
#pragma unroll 4
            for (int jl = 0; jl < 64; ++jl){
                if (jl < limj){
                    float jx1 = __shfl(rx1[jw], jl);
                    float jy1 = __shfl(ry1[jw], jl);
                    float jx2 = __shfl(rx2[jw], jl);
                    float jy2 = __shfl(ry2[jw], jl);
                    float jar = __fmul_rn(__fsub_rn(jx2, jx1), __fsub_rn(jy2, jy1));
#pragma unroll
                    for (int g = 0; g < NG; ++g){
                        if (g > jw) continue;              // j < i for every lane: word stays 0
                        bool jgi = (g < jw) ? true : (lane < jl);
                        float wx = fmaxf(__fsub_rn(fminf(rx2[g], jx2), fmaxf(rx1[g], jx1)), 0.0f);
                        float wy = fmaxf(__fsub_rn(fminf(ry2[g], jy2), fmaxf(ry1[g], jy1)), 0.0f);
                        float inter = __fmul_rn(wx, wy);
                        float den = __fadd_rn(__fsub_rn(__fadd_rn(rar[g], jar), inter), 1e-9f);
                        bool o = (__fdiv_rn(inter, den) > 0.5f) && jgi;
                        mk[g][jw] |= o ? (1ull << jl) : 0ull;
                    }
                }
            }
        }
    }

    // walk: branchless, replicated removed-mask; only words w>=iw are nonzero
    unsigned long long rem[NG];
#pragma unroll
    for (int g = 0; g < NG; ++g) rem[g] = 0ull;
#pragma unroll
    for (int iw = 0; iw < NG; ++iw){
        if (iw*64 < M){
            int limi = M - iw*64; if (limi > 64) limi = 64;
#pragma unroll 4
            for (int il = 0; il < 64; ++il){
                if (il < limi){
                    unsigned long long msk = ((rem[iw] >> il) & 1ull) ? 0ull : ~0ull;
#pragma unroll
                    for (int w = iw; w < NG; ++w){
                        unsigned long long rw = __shfl(mk[iw][w], il);
                        rem[w] |= rw & msk;
                    }
                }
            }
        }
    }
#pragma unroll
    for (int g = 0; g < NG; ++g){
        int r = g*64 + lane;
        unsigned long long rg = rem[g];
        if (r < M) KEEP[base + r] = (unsigned char)(((rg >> lane) & 1ull) ^ 1ull);
    }
}

// K45: per batch, 512 thr (8 waves, one class each): stable 2-pass partition,
//      NG-dispatched register NMS, 2-pass compaction
__global__ void __launch_bounds__(512, 1) k45_nms_out(const float4* __restrict__ dbox,
                                                      const int* __restrict__ dmeta,
                                                      float* __restrict__ out){
    int b = blockIdx.x, tid = threadIdx.x, lane = tid & 63, wv = tid >> 6;
    __shared__ float X1[1024], Y1[1024], X2[1024], Y2[1024], AR[1024];
    __shared__ unsigned char KEEP[1024];
    __shared__ int wq[8][8], wq2[8][8];
    __shared__ int cbs[8], ccn[8];
    __shared__ int wcn[8];
    __shared__ int pbase;

    // phase 1: two entries per thread, stable per-class partition
    int v0 = dmeta[b*PREK + tid];
    int v1 = dmeta[b*PREK + 512 + tid];
    float4 bb0 = dbox[b*PREK + tid];
    float4 bb1 = dbox[b*PREK + 512 + tid];
    bool valid0 = (v0 >= 0), valid1 = (v1 >= 0);
    int lc0 = valid0 ? (v0 & 255) : -1;
    int lc1 = valid1 ? (v1 & 255) : -1;
    KEEP[tid] = 0; KEEP[tid + 512] = 0;
    if (tid == 0) pbase = 0;
    int win0 = 0, win1 = 0;
#pragma unroll
    for (int c = 0; c < 8; ++c){
        unsigned long long bal0 = __ballot(lc0 == c);
        unsigned long long bal1 = __ballot(lc1 == c);
        if (lane == 0){ wq[wv][c] = __popcll(bal0); wq2[wv][c] = __popcll(bal1); }
        if (lc0 == c) win0 = __popcll(bal0 & ((1ull << lane) - 1ull));
        if (lc1 == c) win1 = __popcll(bal1 & ((1ull << lane) - 1ull));
    }
    __syncthreads();
    if (tid < 8){
        int run = 0;
        for (int w2 = 0; w2 < 8; ++w2){ int t = wq[w2][tid];  wq[w2][tid]  = run; run += t; }
        for (int w2 = 0; w2 < 8; ++w2){ int t = wq2[w2][tid]; wq2[w2][tid] = run; run += t; }
        ccn[tid] = run;
    }
    __syncthreads();
    if (tid == 0){
        int run = 0;
        for (int c = 0; c < 8; ++c){ cbs[c] = run; run += ccn[c]; }
    }
    __syncthreads();
    int p0 = 0, p1 = 0;
    if (valid0){
        p0 = cbs[lc0] + wq[wv][lc0] + win0;
        float off = (float)(lc0 << 12);
        float ox1 = __fadd_rn(bb0.x, off), oy1 = __fadd_rn(bb0.y, off);
        float ox2 = __fadd_rn(bb0.z, off), oy2 = __fadd_rn(bb0.w, off);
        X1[p0] = ox1; Y1[p0] = oy1; X2[p0] = ox2; Y2[p0] = oy2;
        AR[p0] = __fmul_rn(__fsub_rn(ox2, ox1), __fsub_rn(oy2, oy1));
    }
    if (valid1){
        p1 = cbs[lc1] + wq2[wv][lc1] + win1;
        float off = (float)(lc1 << 12);
        float ox1 = __fadd_rn(bb1.x, off), oy1 = __fadd_rn(bb1.y, off);
        float ox2 = __fadd_rn(bb1.z, off), oy2 = __fadd_rn(bb1.w, off);
        X1[p1] = ox1; Y1[p1] = oy1; X2[p1] = ox2; Y2[p1] = oy2;
        AR[p1] = __fmul_rn(__fsub_rn(ox2, ox1), __fsub_rn(oy2, oy1));
    }
    __syncthreads();

    // phase 2: NMS, one wave per class, NG dispatch on class size
    {
        int M = ccn[wv], base = cbs[wv];
        if (M > 0){
            if (M <= 128)      nms_reg<2>(X1, Y1, X2, Y2, AR, base, M, lane, KEEP);
            else if (M <= 192) nms_reg<3>(X1, Y1, X2, Y2, AR, base, M, lane, KEEP);
            else if (M <= 256) nms_reg<4>(X1, Y1, X2, Y2, AR, base, M, lane, KEEP);
            else {
                // fallback: wave-serial greedy in LDS
                for (int m = lane; m < M; m += 64) KEEP[base+m] = 0;   // 1 = suppressed
                for (int i = 0; i < M; ++i){
                    if (KEEP[base+i]) continue;
                    float xi1 = X1[base+i], yi1 = Y1[base+i];
                    float xi2 = X2[base+i], yi2 = Y2[base+i], ai = AR[base+i];
                    for (int j = i + 1 + lane; j < M; j += 64){
                        if (KEEP[base+j]) continue;
                        float wx = fmaxf(__fsub_rn(fminf(xi2, X2[base+j]), fmaxf(xi1, X1[base+j])), 0.0f);
                        float wy = fmaxf(__fsub_rn(fminf(yi2, Y2[base+j]), fmaxf(yi1, Y1[base+j])), 0.0f);
                        float inter = __fmul_rn(wx, wy);
                        float den = __fadd_rn(__fsub_rn(__fadd_rn(ai, AR[base+j]), inter), 1e-9f);
                        if (__fdiv_rn(inter, den) > 0.5f) KEEP[base+j] = 1;
                    }
                }
                for (int m = lane; m < M; m += 64) KEEP[base+m] ^= 1;  // -> 1 = keep
            }
        }
    }
    __syncthreads();

    // phase 3: rank-ordered compaction to first 300 (two passes)
    float* boxes  = out;
    float* scores = out + Bb*POSTK*4;
    float* labs   = out + Bb*POSTK*5;
#pragma unroll
    for (int pass = 0; pass < 2; ++pass){
        bool vld   = pass ? valid1 : valid0;
        int  pp    = pass ? p1 : p0;
        int  lcc   = pass ? lc1 : lc0;
        int  vv    = pass ? v1 : v0;
        float4 bbb = pass ? bb1 : bb0;
        bool kp = vld && (KEEP[pp] != 0);
        unsigned long long bal = __ballot(kp);
        if (lane == 0) wcn[wv] = __popcll(bal);
        __syncthreads();
        if (tid == 0){
            int r = pbase;
            for (int w2 = 0; w2 < 8; ++w2){ int t = wcn[w2]; wcn[w2] = r; r += t; }
            pbase = r;
        }
        __syncthreads();
        int pos = wcn[wv] + __popcll(bal & ((1ull << lane) - 1ull));
        if (kp && pos < POSTK){
            float sval = __fmul_rn((float)((vv >> 8) - 128), 0.0625f);
            int o = (b*POSTK + pos)*4;
            boxes[o+0] = bbb.x; boxes[o+1] = bbb.y; boxes[o+2] = bbb.z; boxes[o+3] = bbb.w;
            scores[b*POSTK + pos] = sval;
            labs[b*POSTK + pos] = (float)lcc;
        }
        __syncthreads();
    }
    int tot = pbase < POSTK ? pbase : POSTK;
    if (tid >= tot && tid < POSTK){
        int o = (b*POSTK + tid)*4;
        boxes[o+0] = 0.f; boxes[o+1] = 0.f; boxes[o+2] = 0.f; boxes[o+3] = 0.f;
        scores[b*POSTK + tid] = 0.f;
        labs[b*POSTK + tid] = -1.0f;
    }
}

extern "C" void kernel_launch(void* const* d_in, const int* in_sizes, int n_in,
                              void* d_out, int out_size, void* d_ws, size_t ws_size,
                              hipStream_t stream) {
    const int*   data    = (const int*)d_in[0];
    const float* anchors = (const float*)d_in[1];
    const int*   etab    = (const int*)d_in[2];
    float* out = (float*)d_out;

    char* ws = (char*)d_ws;
    size_t off = 0;
    auto alloc = [&](size_t bytes)->char*{ char* p = ws + off; off += (bytes + 255) & ~(size_t)255; return p; };
    unsigned short* sc16 = (unsigned short*)alloc((size_t)Bb*8*16384*2);   // 2 MB
    int* chist           = (int*)alloc((size_t)Bb*NCHUNK*NBIN*4);          // 1.9 MB
    int* gt              = (int*)alloc((size_t)Bb*128*4);
    int* Tb_             = (int*)alloc((size_t)Bb*4);
    float4* dbox         = (float4*)alloc((size_t)Bb*PREK*16);             // 128 KB
    int* dmeta           = (int*)alloc((size_t)Bb*PREK*4);                 // 32 KB
    (void)ws_size; (void)in_sizes; (void)n_in; (void)out_size;

    k1_scores<<<Bb*128, 256, 0, stream>>>(data, sc16, chist);
    k2_select<<<Bb, 1024, 0, stream>>>(chist, gt, Tb_, dmeta);
    k3_rank<<<Bb*NCHUNK, 256, 0, stream>>>(sc16, chist, gt, Tb_, data, anchors, etab, dbox, dmeta);
    k45_nms_out<<<Bb, 512, 0, stream>>>(dbox, dmeta, out);
}